// Round 1
// baseline (638.779 us; speedup 1.0000x reference)
//
#include <hip/hip_runtime.h>
#include <stdint.h>

#define Bn 2048
#define Tn 512
#define An 32
#define Hn 16

typedef __attribute__((ext_vector_type(8))) short bf16x8;
typedef __attribute__((ext_vector_type(4))) float f32x4;

union FragU { bf16x8 v; uint32_t u[4]; };

static __device__ __forceinline__ float sigm(float x){
  // 1/(1+2^(-x*log2e)) ; v_exp_f32 + v_rcp_f32, ~1 ulp each
  return __builtin_amdgcn_rcpf(1.0f + __builtin_amdgcn_exp2f(x * -1.44269504088896f));
}
static __device__ __forceinline__ float tanhx(float x){
  // 1 - 2/(1+2^(2x*log2e))
  return 1.0f - 2.0f * __builtin_amdgcn_rcpf(1.0f + __builtin_amdgcn_exp2f(x * 2.88539008177793f));
}

// pack bf16-truncations of (a,b): low16 = a_hi16, high16 = b_hi16
static __device__ __forceinline__ uint32_t pack_hi16(float a, float b){
  return (__float_as_uint(b) & 0xFFFF0000u) | (__float_as_uint(a) >> 16);
}

// split 8 fp32 into hi/lo bf16 fragments (element e of frag = k index e; even k in low half)
static __device__ __forceinline__ void split8(const float* s, FragU& hi, FragU& lo){
#pragma unroll
  for (int d = 0; d < 4; ++d){
    float a = s[2*d], b = s[2*d+1];
    float ah = __uint_as_float(__float_as_uint(a) & 0xFFFF0000u);
    float bh = __uint_as_float(__float_as_uint(b) & 0xFFFF0000u);
    hi.u[d] = pack_hi16(a, b);
    lo.u[d] = pack_hi16(a - ah, b - bh);
  }
}

// combine low16 halves / high16 halves of (even,odd) packed dwords
static __device__ __forceinline__ uint32_t plo(uint32_t e, uint32_t o){
  return __builtin_amdgcn_perm(o, e, 0x05040100u);
}
static __device__ __forceinline__ uint32_t phi(uint32_t e, uint32_t o){
  return __builtin_amdgcn_perm(o, e, 0x07060302u);
}

static __device__ __forceinline__ f32x4 MF(const FragU& a, const FragU& b, f32x4 c){
  return __builtin_amdgcn_mfma_f32_16x16x32_bf16(a.v, b.v, c, 0, 0, 0);
}

__global__ __launch_bounds__(128, 1)
void lstm_fused(const float* __restrict__ xin,   // [B,T,32]
                const float* __restrict__ masks, // [B,T]
                const float* __restrict__ h0,    // [B,16]
                const float* __restrict__ c0,    // [B,16]
                const float* __restrict__ w_ih,  // [64,32]
                const float* __restrict__ w_hh,  // [64,16]
                const float* __restrict__ b_ih,  // [64]
                const float* __restrict__ b_hh,  // [64]
                const float* __restrict__ w_act, // [32,16]
                const float* __restrict__ b_act, // [32]
                const float* __restrict__ w_cr,  // [16]
                const float* __restrict__ b_cr,  // [1]
                float* __restrict__ actor,       // [B,T,32]
                float* __restrict__ critic,      // [B,T]
                float* __restrict__ hT,          // [B,16]
                float* __restrict__ cT)          // [B,16]
{
  // gate exchange: [parity][tile 0..3][lane*4] fp32 (8 KiB)
  __shared__ float gbuf[2][4][256];
  // h state (packed hi|lo bf16), per wave, padded stride 20 dwords (2.5 KiB)
  __shared__ uint32_t hbuf[2][16*20];

  const int tid = threadIdx.x;
  const int w = tid >> 6;        // wave 0: tiles i,f ; wave 1: tiles g,o
  const int l = tid & 63;
  const int q = l >> 4;          // quad
  const int n = l & 15;          // batch col / A-row index
  const int b0 = blockIdx.x * 16;
  const int colbase = (q & 1) * 8;
  const bool hiQuad = (q < 2);

  // ---------------- weight fragments (loaded once) ----------------
  // A-frag layout (16x16x32): A[m=lane&15][k=q*8+j]
  FragU wihH[2], wihL[2], whhA1[2], whhA2[2];
  f32x4 bias[2];
#pragma unroll
  for (int tt = 0; tt < 2; ++tt){
    const int g = 2*w + tt;
    float tmp[8];
#pragma unroll
    for (int j = 0; j < 8; ++j) tmp[j] = w_ih[(g*16 + n)*32 + q*8 + j];
    split8(tmp, wihH[tt], wihL[tt]);
#pragma unroll
    for (int j = 0; j < 8; ++j) tmp[j] = w_hh[(g*16 + n)*16 + colbase + j];
    FragU hh, hl; split8(tmp, hh, hl);
#pragma unroll
    for (int d = 0; d < 4; ++d){
      whhA1[tt].u[d] = hiQuad ? hh.u[d] : hl.u[d];  // [Whh_hi | Whh_lo]
      whhA2[tt].u[d] = hiQuad ? hh.u[d] : 0u;       // [Whh_hi | 0]
    }
#pragma unroll
    for (int r = 0; r < 4; ++r)
      bias[tt][r] = b_ih[g*16 + q*4 + r] + b_hh[g*16 + q*4 + r];
  }
  FragU waA1, waA2;
  {
    float tmp[8];
#pragma unroll
    for (int j = 0; j < 8; ++j) tmp[j] = w_act[(w*16 + n)*16 + colbase + j];
    FragU hh, hl; split8(tmp, hh, hl);
#pragma unroll
    for (int d = 0; d < 4; ++d){
      waA1.u[d] = hiQuad ? hh.u[d] : hl.u[d];
      waA2.u[d] = hiQuad ? hh.u[d] : 0u;
    }
  }
  f32x4 biasA;
#pragma unroll
  for (int r = 0; r < 4; ++r) biasA[r] = b_act[w*16 + q*4 + r];
  FragU wcA1, wcA2;   // critic: row 0 = w_critic, rows 1..15 = 0
  {
    float tmp[8];
#pragma unroll
    for (int j = 0; j < 8; ++j) tmp[j] = (n == 0) ? w_cr[colbase + j] : 0.0f;
    FragU hh, hl; split8(tmp, hh, hl);
#pragma unroll
    for (int d = 0; d < 4; ++d){
      wcA1.u[d] = hiQuad ? hh.u[d] : hl.u[d];
      wcA2.u[d] = hiQuad ? hh.u[d] : 0u;
    }
  }
  const float bcr = b_cr[0];

  // ---------------- initial state ----------------
  float cs[4], hs[4];
#pragma unroll
  for (int r = 0; r < 4; ++r){
    hs[r] = h0[(b0 + n)*16 + q*4 + r];   // state (unit=q*4+r, batch=n)
    cs[r] = c0[(b0 + n)*16 + q*4 + r];
  }
  uint32_t* hb = hbuf[w];
  {
    uint32_t pk0 = pack_hi16(hs[0], hs[0] - __uint_as_float(__float_as_uint(hs[0]) & 0xFFFF0000u));
    // pack per value: low16=hi(h), high16=bf16(residual)
    uint32_t pk[4];
#pragma unroll
    for (int r = 0; r < 4; ++r){
      float hh_ = __uint_as_float(__float_as_uint(hs[r]) & 0xFFFF0000u);
      pk[r] = (__float_as_uint(hs[r] - hh_) & 0xFFFF0000u) | (__float_as_uint(hs[r]) >> 16);
    }
    (void)pk0;
    *(uint4*)&hb[n*20 + q*4] = make_uint4(pk[0], pk[1], pk[2], pk[3]);
  }
  FragU BHh, BHl;  // B-frags: [Hh;Hh] and [Hl;Hl] (duplication automatic via (q&1) row select)
  {
    uint4 d0 = *(uint4*)&hb[n*20 + colbase];
    uint4 d1 = *(uint4*)&hb[n*20 + colbase + 4];
    BHh.u[0] = plo(d0.x, d0.y); BHh.u[1] = plo(d0.z, d0.w);
    BHh.u[2] = plo(d1.x, d1.y); BHh.u[3] = plo(d1.z, d1.w);
    BHl.u[0] = phi(d0.x, d0.y); BHl.u[1] = phi(d0.z, d0.w);
    BHl.u[2] = phi(d1.x, d1.y); BHl.u[3] = phi(d1.z, d1.w);
  }

  const f32x4 zero4 = {0.f, 0.f, 0.f, 0.f};
  const size_t xbase = ((size_t)(b0 + n) * Tn) * 32 + q*8;
  float4 xa = *(const float4*)&xin[xbase];
  float4 xb = *(const float4*)&xin[xbase + 4];
  float mNext = masks[(size_t)(b0 + n) * Tn];

  for (int t = 0; t < Tn; ++t){
    const float m = mNext;

    // x fragments (B[k=q*8+j][n] = x[b0+n][t][k]), bf16 hi/lo split
    FragU Xh, Xl;
    {
      float s[8] = {xa.x, xa.y, xa.z, xa.w, xb.x, xb.y, xb.z, xb.w};
      split8(s, Xh, Xl);
    }

    // gates: acc_x = Wih_h*Xh + Wih_h*Xl + Wih_l*Xh + bias ; acc_h (unmasked h terms)
    f32x4 ax0 = MF(wihH[0], Xh, bias[0]);
    f32x4 ax1 = MF(wihH[1], Xh, bias[1]);
    ax0 = MF(wihH[0], Xl, ax0);  ax0 = MF(wihL[0], Xh, ax0);
    ax1 = MF(wihH[1], Xl, ax1);  ax1 = MF(wihL[1], Xh, ax1);
    f32x4 ah0 = MF(whhA1[0], BHh, zero4);  ah0 = MF(whhA2[0], BHl, ah0);
    f32x4 ah1 = MF(whhA1[1], BHh, zero4);  ah1 = MF(whhA2[1], BHl, ah1);

    // prefetch next x / mask while MFMAs are in flight
    const int tn = (t + 1 < Tn) ? (t + 1) : t;
    xa = *(const float4*)&xin[xbase + (size_t)tn * 32];
    xb = *(const float4*)&xin[xbase + (size_t)tn * 32 + 4];
    mNext = masks[(size_t)(b0 + n) * Tn + tn];

    // activations on own tiles (mask folds in: gate = acc_x + m*acc_h)
    float own0[4], own1[4];
#pragma unroll
    for (int r = 0; r < 4; ++r){
      float g0v = ax0[r] + m * ah0[r];
      float g1v = ax1[r] + m * ah1[r];
      if (w == 0){ own0[r] = sigm(g0v);  own1[r] = sigm(g1v); }   // i, f
      else       { own0[r] = tanhx(g0v); own1[r] = sigm(g1v); }   // g, o
    }

    // exchange activated gates (double-buffered by parity -> one barrier/step)
    const int par = t & 1;
    *(float4*)&gbuf[par][2*w + 0][l*4] = make_float4(own0[0], own0[1], own0[2], own0[3]);
    *(float4*)&gbuf[par][2*w + 1][l*4] = make_float4(own1[0], own1[1], own1[2], own1[3]);
    __syncthreads();
    float4 oth0 = *(float4*)&gbuf[par][2*(1-w) + 0][l*4];
    float4 oth1 = *(float4*)&gbuf[par][2*(1-w) + 1][l*4];

    float iv[4], fv[4], gv[4], ov[4];
    if (w == 0){
      iv[0]=own0[0]; iv[1]=own0[1]; iv[2]=own0[2]; iv[3]=own0[3];
      fv[0]=own1[0]; fv[1]=own1[1]; fv[2]=own1[2]; fv[3]=own1[3];
      gv[0]=oth0.x;  gv[1]=oth0.y;  gv[2]=oth0.z;  gv[3]=oth0.w;
      ov[0]=oth1.x;  ov[1]=oth1.y;  ov[2]=oth1.z;  ov[3]=oth1.w;
    } else {
      gv[0]=own0[0]; gv[1]=own0[1]; gv[2]=own0[2]; gv[3]=own0[3];
      ov[0]=own1[0]; ov[1]=own1[1]; ov[2]=own1[2]; ov[3]=own1[3];
      iv[0]=oth0.x;  iv[1]=oth0.y;  iv[2]=oth0.z;  iv[3]=oth0.w;
      fv[0]=oth1.x;  fv[1]=oth1.y;  fv[2]=oth1.z;  fv[3]=oth1.w;
    }

    // state update (lane-local), pack new h (hi|lo bf16)
    uint32_t pk[4];
#pragma unroll
    for (int r = 0; r < 4; ++r){
      float cm = cs[r] * m;
      float c2 = fv[r] * cm + iv[r] * gv[r];
      float h2 = ov[r] * tanhx(c2);
      cs[r] = c2;
      hs[r] = h2;
      float hh_ = __uint_as_float(__float_as_uint(h2) & 0xFFFF0000u);
      pk[r] = (__float_as_uint(h2 - hh_) & 0xFFFF0000u) | (__float_as_uint(h2) >> 16);
    }
    *(uint4*)&hb[n*20 + q*4] = make_uint4(pk[0], pk[1], pk[2], pk[3]);

    // rebuild B-frags from new h (intra-wave LDS round trip; serves heads now + gates next step)
    {
      uint4 d0 = *(uint4*)&hb[n*20 + colbase];
      uint4 d1 = *(uint4*)&hb[n*20 + colbase + 4];
      BHh.u[0] = plo(d0.x, d0.y); BHh.u[1] = plo(d0.z, d0.w);
      BHh.u[2] = plo(d1.x, d1.y); BHh.u[3] = plo(d1.z, d1.w);
      BHl.u[0] = phi(d0.x, d0.y); BHl.u[1] = phi(d0.z, d0.w);
      BHl.u[2] = phi(d1.x, d1.y); BHl.u[3] = phi(d1.z, d1.w);
    }

    // fused heads: actor tile (wave0: a 0..15, wave1: a 16..31), critic on wave1
    f32x4 aacc = MF(waA1, BHh, biasA);
    aacc = MF(waA2, BHl, aacc);
    *(f32x4*)&actor[((size_t)(b0 + n) * Tn + t) * 32 + w*16 + q*4] = aacc;
    if (w == 1){
      f32x4 cacc = MF(wcA1, BHh, zero4);
      cacc = MF(wcA2, BHl, cacc);
      if (l < 16) critic[(size_t)(b0 + l) * Tn + t] = cacc[0] + bcr;
    }
  }

  if (w == 0){
    *(float4*)&hT[(b0 + n)*16 + q*4] = make_float4(hs[0], hs[1], hs[2], hs[3]);
    *(float4*)&cT[(b0 + n)*16 + q*4] = make_float4(cs[0], cs[1], cs[2], cs[3]);
  }
}

extern "C" void kernel_launch(void* const* d_in, const int* in_sizes, int n_in,
                              void* d_out, int out_size, void* d_ws, size_t ws_size,
                              hipStream_t stream) {
  (void)in_sizes; (void)n_in; (void)out_size; (void)d_ws; (void)ws_size;
  const float* xin   = (const float*)d_in[0];
  const float* masks = (const float*)d_in[1];
  const float* h0    = (const float*)d_in[2];
  const float* c0    = (const float*)d_in[3];
  const float* w_ih  = (const float*)d_in[4];
  const float* w_hh  = (const float*)d_in[5];
  const float* b_ih  = (const float*)d_in[6];
  const float* b_hh  = (const float*)d_in[7];
  const float* w_act = (const float*)d_in[8];
  const float* b_act = (const float*)d_in[9];
  const float* w_cr  = (const float*)d_in[10];
  const float* b_cr  = (const float*)d_in[11];

  float* out    = (float*)d_out;
  float* actor  = out;                                   // [B,T,32]
  float* critic = out + (size_t)Bn * Tn * An;            // [B,T]
  float* hT     = critic + (size_t)Bn * Tn;              // [B,16]
  float* cT     = hT + (size_t)Bn * Hn;                  // [B,16]

  lstm_fused<<<Bn/16, 128, 0, stream>>>(xin, masks, h0, c0, w_ih, w_hh, b_ih, b_hh,
                                        w_act, b_act, w_cr, b_cr,
                                        actor, critic, hT, cT);
}

// Round 2
// 610.972 us; speedup vs baseline: 1.0455x; 1.0455x over previous
//
#include <hip/hip_runtime.h>
#include <stdint.h>

#define Bn 2048
#define Tn 512
#define An 32
#define Hn 16
#define MSTR 524   // mask LDS row stride (dwords): 524%4==0 (b128 align), 12n+t banks -> only 2-way aliasing (free)

typedef __attribute__((ext_vector_type(8))) short bf16x8;
typedef __attribute__((ext_vector_type(4))) float f32x4;

union FragU { bf16x8 v; uint32_t u[4]; };

static __device__ __forceinline__ float sigm(float x){
  return __builtin_amdgcn_rcpf(1.0f + __builtin_amdgcn_exp2f(x * -1.44269504088896f));
}
static __device__ __forceinline__ float tanhx(float x){
  return 1.0f - 2.0f * __builtin_amdgcn_rcpf(1.0f + __builtin_amdgcn_exp2f(x * 2.88539008177793f));
}
static __device__ __forceinline__ uint32_t pack_hi16(float a, float b){
  return (__float_as_uint(b) & 0xFFFF0000u) | (__float_as_uint(a) >> 16);
}
// split 8 fp32 into hi/lo bf16 fragments (element e = k index e; even k low half of dword)
static __device__ __forceinline__ void split8(const float* s, FragU& hi, FragU& lo){
#pragma unroll
  for (int d = 0; d < 4; ++d){
    float a = s[2*d], b = s[2*d+1];
    float ah = __uint_as_float(__float_as_uint(a) & 0xFFFF0000u);
    float bh = __uint_as_float(__float_as_uint(b) & 0xFFFF0000u);
    hi.u[d] = pack_hi16(a, b);
    lo.u[d] = pack_hi16(a - ah, b - bh);
  }
}
static __device__ __forceinline__ uint32_t plo(uint32_t e, uint32_t o){
  return __builtin_amdgcn_perm(o, e, 0x05040100u);
}
static __device__ __forceinline__ uint32_t phi(uint32_t e, uint32_t o){
  return __builtin_amdgcn_perm(o, e, 0x07060302u);
}
static __device__ __forceinline__ f32x4 MF(const FragU& a, const FragU& b, f32x4 c){
  return __builtin_amdgcn_mfma_f32_16x16x32_bf16(a.v, b.v, c, 0, 0, 0);
}
// pack h into (bf16(h) | bf16(residual)) dwords, one per unit r
static __device__ __forceinline__ void packH(const float* hs, uint32_t* pk){
#pragma unroll
  for (int r = 0; r < 4; ++r){
    float hh_ = __uint_as_float(__float_as_uint(hs[r]) & 0xFFFF0000u);
    pk[r] = (__float_as_uint(hs[r] - hh_) & 0xFFFF0000u) | (__float_as_uint(hs[r]) >> 16);
  }
}
// rebuild B-fragments (Hh dup, Hl dup) from packed state via cross-lane bpermute (no LDS round trip)
static __device__ __forceinline__ void buildBH(const uint32_t* pk, int srcA, int srcB,
                                               FragU& BHh, FragU& BHl){
  uint32_t d0 = (uint32_t)__builtin_amdgcn_ds_bpermute(srcA, (int)pk[0]);
  uint32_t d1 = (uint32_t)__builtin_amdgcn_ds_bpermute(srcA, (int)pk[1]);
  uint32_t d2 = (uint32_t)__builtin_amdgcn_ds_bpermute(srcA, (int)pk[2]);
  uint32_t d3 = (uint32_t)__builtin_amdgcn_ds_bpermute(srcA, (int)pk[3]);
  uint32_t d4 = (uint32_t)__builtin_amdgcn_ds_bpermute(srcB, (int)pk[0]);
  uint32_t d5 = (uint32_t)__builtin_amdgcn_ds_bpermute(srcB, (int)pk[1]);
  uint32_t d6 = (uint32_t)__builtin_amdgcn_ds_bpermute(srcB, (int)pk[2]);
  uint32_t d7 = (uint32_t)__builtin_amdgcn_ds_bpermute(srcB, (int)pk[3]);
  BHh.u[0] = plo(d0, d1); BHh.u[1] = plo(d2, d3);
  BHh.u[2] = plo(d4, d5); BHh.u[3] = plo(d6, d7);
  BHl.u[0] = phi(d0, d1); BHl.u[1] = phi(d2, d3);
  BHl.u[2] = phi(d4, d5); BHl.u[3] = phi(d6, d7);
}

__global__ __launch_bounds__(64, 1)
void lstm_fused(const float* __restrict__ xin,   // [B,T,32]
                const float* __restrict__ masks, // [B,T]
                const float* __restrict__ h0,    // [B,16]
                const float* __restrict__ c0,    // [B,16]
                const float* __restrict__ w_ih,  // [64,32]
                const float* __restrict__ w_hh,  // [64,16]
                const float* __restrict__ b_ih,  // [64]
                const float* __restrict__ b_hh,  // [64]
                const float* __restrict__ w_act, // [32,16]
                const float* __restrict__ b_act, // [32]
                const float* __restrict__ w_cr,  // [16]
                const float* __restrict__ b_cr,  // [1]
                float* __restrict__ actor,       // [B,T,32]
                float* __restrict__ critic,      // [B,T]
                float* __restrict__ hT,          // [B,16]
                float* __restrict__ cT)          // [B,16]
{
  __shared__ float mlds[16 * MSTR];   // masks, layout [n][t], ~33.5 KB

  const int l = threadIdx.x;          // single wave per block
  const int q = l >> 4;               // quad
  const int n = l & 15;               // batch col
  const int b0 = blockIdx.x * 16;
  const int colbase = (q & 1) * 8;
  const bool hiQuad = (q < 2);

  // ---- stage all masks for this block's 16 batch rows into LDS (one time) ----
#pragma unroll 4
  for (int it = 0; it < 32; ++it){
    const int t0 = q * 4 + it * 16;
    float4 v = *(const float4*)&masks[(size_t)(b0 + n) * Tn + t0];
    *(float4*)&mlds[n * MSTR + t0] = v;
  }
  __syncthreads();  // one wave: compiles to lgkm wait + immediate barrier; once per kernel

  // ---- weight fragments (loaded once) ----
  // A-frag (16x16x32): A[m=lane&15][k=q*8+j]
  FragU wihH[4], wihL[4], whhA1[4], whhA2[4];
  f32x4 bias[4];
#pragma unroll
  for (int g = 0; g < 4; ++g){
    float tmp[8];
#pragma unroll
    for (int j = 0; j < 8; ++j) tmp[j] = w_ih[(g*16 + n)*32 + q*8 + j];
    split8(tmp, wihH[g], wihL[g]);
#pragma unroll
    for (int j = 0; j < 8; ++j) tmp[j] = w_hh[(g*16 + n)*16 + colbase + j];
    FragU hh, hl; split8(tmp, hh, hl);
#pragma unroll
    for (int d = 0; d < 4; ++d){
      whhA1[g].u[d] = hiQuad ? hh.u[d] : hl.u[d];  // [Whh_hi | Whh_lo]
      whhA2[g].u[d] = hiQuad ? hh.u[d] : 0u;       // [Whh_hi | 0]
    }
#pragma unroll
    for (int r = 0; r < 4; ++r)
      bias[g][r] = b_ih[g*16 + q*4 + r] + b_hh[g*16 + q*4 + r];
  }
  FragU waA1[2], waA2[2];
  f32x4 biasA[2];
#pragma unroll
  for (int tt = 0; tt < 2; ++tt){
    float tmp[8];
#pragma unroll
    for (int j = 0; j < 8; ++j) tmp[j] = w_act[(tt*16 + n)*16 + colbase + j];
    FragU hh, hl; split8(tmp, hh, hl);
#pragma unroll
    for (int d = 0; d < 4; ++d){
      waA1[tt].u[d] = hiQuad ? hh.u[d] : hl.u[d];
      waA2[tt].u[d] = hiQuad ? hh.u[d] : 0u;
    }
#pragma unroll
    for (int r = 0; r < 4; ++r) biasA[tt][r] = b_act[tt*16 + q*4 + r];
  }
  FragU wcA1, wcA2;   // critic: row 0 = w_critic, rows 1..15 = 0
  {
    float tmp[8];
#pragma unroll
    for (int j = 0; j < 8; ++j) tmp[j] = (n == 0) ? w_cr[colbase + j] : 0.0f;
    FragU hh, hl; split8(tmp, hh, hl);
#pragma unroll
    for (int d = 0; d < 4; ++d){
      wcA1.u[d] = hiQuad ? hh.u[d] : hl.u[d];
      wcA2.u[d] = hiQuad ? hh.u[d] : 0u;
    }
  }
  const float bcr = b_cr[0];

  // bpermute source addresses (bytes): units colbase+0..3 from quad (q&1)*2, +4..7 from next quad
  const int srcA = (((q & 1) * 2) * 16 + n) * 4;
  const int srcB = srcA + 64;

  // ---- initial state ----
  float cs[4], hs[4];
#pragma unroll
  for (int r = 0; r < 4; ++r){
    hs[r] = h0[(b0 + n)*16 + q*4 + r];
    cs[r] = c0[(b0 + n)*16 + q*4 + r];
  }
  uint32_t pk[4];
  packH(hs, pk);
  FragU BHh, BHl;
  buildBH(pk, srcA, srcB, BHh, BHl);

  const f32x4 zero4 = {0.f, 0.f, 0.f, 0.f};

  // ---- x prefetch: depth-4 rotating register queue ----
  const size_t xrow = (size_t)(b0 + n) * Tn * 32 + q * 8;
  float4 xA[4], xB[4];
#pragma unroll
  for (int u = 0; u < 4; ++u){
    xA[u] = *(const float4*)&xin[xrow + (size_t)u * 32];
    xB[u] = *(const float4*)&xin[xrow + (size_t)u * 32 + 4];
  }

  for (int t0 = 0; t0 < Tn; t0 += 4){
#pragma unroll
    for (int u = 0; u < 4; ++u){
      const int t = t0 + u;
      const float m = mlds[n * MSTR + t];

      // x fragments
      FragU Xh, Xl;
      {
        float s[8] = {xA[u].x, xA[u].y, xA[u].z, xA[u].w,
                      xB[u].x, xB[u].y, xB[u].z, xB[u].w};
        split8(s, Xh, Xl);
      }
      // prefetch t+4 into freed slot (issue early; no barrier anywhere -> partial vmcnt waits only)
      {
        const int tn = (t + 4 < Tn) ? (t + 4) : t;
        xA[u] = *(const float4*)&xin[xrow + (size_t)tn * 32];
        xB[u] = *(const float4*)&xin[xrow + (size_t)tn * 32 + 4];
      }

      // gates: x-part (3 MFMA/tile) + h-part (2 MFMA/tile)
      f32x4 ax0 = MF(wihH[0], Xh, bias[0]);
      f32x4 ax1 = MF(wihH[1], Xh, bias[1]);
      f32x4 ax2 = MF(wihH[2], Xh, bias[2]);
      f32x4 ax3 = MF(wihH[3], Xh, bias[3]);
      ax0 = MF(wihH[0], Xl, ax0);  ax0 = MF(wihL[0], Xh, ax0);
      ax1 = MF(wihH[1], Xl, ax1);  ax1 = MF(wihL[1], Xh, ax1);
      ax2 = MF(wihH[2], Xl, ax2);  ax2 = MF(wihL[2], Xh, ax2);
      ax3 = MF(wihH[3], Xl, ax3);  ax3 = MF(wihL[3], Xh, ax3);
      f32x4 ah0 = MF(whhA1[0], BHh, zero4);  ah0 = MF(whhA2[0], BHl, ah0);
      f32x4 ah1 = MF(whhA1[1], BHh, zero4);  ah1 = MF(whhA2[1], BHl, ah1);
      f32x4 ah2 = MF(whhA1[2], BHh, zero4);  ah2 = MF(whhA2[2], BHl, ah2);
      f32x4 ah3 = MF(whhA1[3], BHh, zero4);  ah3 = MF(whhA2[3], BHl, ah3);

      // activations (mask folds in algebraically: gate = ax + m*ah)
      float iv[4], fv[4], gv[4], ov[4];
#pragma unroll
      for (int r = 0; r < 4; ++r){
        iv[r] = sigm (ax0[r] + m * ah0[r]);
        fv[r] = sigm (ax1[r] + m * ah1[r]);
        gv[r] = tanhx(ax2[r] + m * ah2[r]);
        ov[r] = sigm (ax3[r] + m * ah3[r]);
      }

      // state update (fully lane-local) + pack new h
#pragma unroll
      for (int r = 0; r < 4; ++r){
        float c2 = fv[r] * (cs[r] * m) + iv[r] * gv[r];
        float h2 = ov[r] * tanhx(c2);
        cs[r] = c2;
        hs[r] = h2;
      }
      packH(hs, pk);
      buildBH(pk, srcA, srcB, BHh, BHl);   // serves heads now + next step's h-MFMAs

      // fused heads
      f32x4 a0 = MF(waA1[0], BHh, biasA[0]);  a0 = MF(waA2[0], BHl, a0);
      f32x4 a1 = MF(waA1[1], BHh, biasA[1]);  a1 = MF(waA2[1], BHl, a1);
      const size_t obase = ((size_t)(b0 + n) * Tn + t) * 32;
      *(f32x4*)&actor[obase + q*4]      = a0;
      *(f32x4*)&actor[obase + 16 + q*4] = a1;
      f32x4 cc = MF(wcA1, BHh, zero4);  cc = MF(wcA2, BHl, cc);
      if (q == 0) critic[(size_t)(b0 + n) * Tn + t] = cc[0] + bcr;
    }
  }

  *(float4*)&hT[(b0 + n)*16 + q*4] = make_float4(hs[0], hs[1], hs[2], hs[3]);
  *(float4*)&cT[(b0 + n)*16 + q*4] = make_float4(cs[0], cs[1], cs[2], cs[3]);
}

extern "C" void kernel_launch(void* const* d_in, const int* in_sizes, int n_in,
                              void* d_out, int out_size, void* d_ws, size_t ws_size,
                              hipStream_t stream) {
  (void)in_sizes; (void)n_in; (void)out_size; (void)d_ws; (void)ws_size;
  const float* xin   = (const float*)d_in[0];
  const float* masks = (const float*)d_in[1];
  const float* h0    = (const float*)d_in[2];
  const float* c0    = (const float*)d_in[3];
  const float* w_ih  = (const float*)d_in[4];
  const float* w_hh  = (const float*)d_in[5];
  const float* b_ih  = (const float*)d_in[6];
  const float* b_hh  = (const float*)d_in[7];
  const float* w_act = (const float*)d_in[8];
  const float* b_act = (const float*)d_in[9];
  const float* w_cr  = (const float*)d_in[10];
  const float* b_cr  = (const float*)d_in[11];

  float* out    = (float*)d_out;
  float* actor  = out;                                   // [B,T,32]
  float* critic = out + (size_t)Bn * Tn * An;            // [B,T]
  float* hT     = critic + (size_t)Bn * Tn;              // [B,16]
  float* cT     = hT + (size_t)Bn * Hn;                  // [B,16]

  lstm_fused<<<Bn/16, 64, 0, stream>>>(xin, masks, h0, c0, w_ih, w_hh, b_ih, b_hh,
                                       w_act, b_act, w_cr, b_cr,
                                       actor, critic, hT, cT);
}

// Round 3
// 538.500 us; speedup vs baseline: 1.1862x; 1.1346x over previous
//
#include <hip/hip_runtime.h>
#include <stdint.h>

#define Bn 2048
#define Tn 512
#define An 32
#define Hn 16

typedef __attribute__((ext_vector_type(8))) short bf16x8;
typedef __attribute__((ext_vector_type(4))) float f32x4;

union FragU { bf16x8 v; uint32_t u[4]; };

// raw barrier: lgkm-only drain (LDS visibility), NO vmcnt drain -> global prefetch stays in flight
#define BAR() __asm__ volatile("s_waitcnt lgkmcnt(0)\n\ts_barrier" ::: "memory")

static __device__ __forceinline__ float sigm(float x){
  return __builtin_amdgcn_rcpf(1.0f + __builtin_amdgcn_exp2f(x * -1.44269504088896f));
}
static __device__ __forceinline__ float tanhx(float x){
  return 1.0f - 2.0f * __builtin_amdgcn_rcpf(1.0f + __builtin_amdgcn_exp2f(x * 2.88539008177793f));
}
static __device__ __forceinline__ uint32_t pack_hi16(float a, float b){
  return (__float_as_uint(b) & 0xFFFF0000u) | (__float_as_uint(a) >> 16);
}
// split 8 fp32 into hi/lo bf16 fragments (element e = k index e; even k low half of dword)
static __device__ __forceinline__ void split8(const float* s, FragU& hi, FragU& lo){
#pragma unroll
  for (int d = 0; d < 4; ++d){
    float a = s[2*d], b = s[2*d+1];
    float ah = __uint_as_float(__float_as_uint(a) & 0xFFFF0000u);
    float bh = __uint_as_float(__float_as_uint(b) & 0xFFFF0000u);
    hi.u[d] = pack_hi16(a, b);
    lo.u[d] = pack_hi16(a - ah, b - bh);
  }
}
static __device__ __forceinline__ uint32_t plo(uint32_t e, uint32_t o){
  return __builtin_amdgcn_perm(o, e, 0x05040100u);
}
static __device__ __forceinline__ uint32_t phi(uint32_t e, uint32_t o){
  return __builtin_amdgcn_perm(o, e, 0x07060302u);
}
static __device__ __forceinline__ f32x4 MF(const FragU& a, const FragU& b, f32x4 c){
  return __builtin_amdgcn_mfma_f32_16x16x32_bf16(a.v, b.v, c, 0, 0, 0);
}
static __device__ __forceinline__ void packH(const float* hs, uint32_t* pk){
#pragma unroll
  for (int r = 0; r < 4; ++r){
    float hh_ = __uint_as_float(__float_as_uint(hs[r]) & 0xFFFF0000u);
    pk[r] = (__float_as_uint(hs[r] - hh_) & 0xFFFF0000u) | (__float_as_uint(hs[r]) >> 16);
  }
}
// rebuild B-fragments (Hh dup, Hl dup) from packed state via wave-wide bpermute
static __device__ __forceinline__ void buildBH(const uint32_t* pk, int srcA, int srcB,
                                               FragU& BHh, FragU& BHl){
  uint32_t d0 = (uint32_t)__builtin_amdgcn_ds_bpermute(srcA, (int)pk[0]);
  uint32_t d1 = (uint32_t)__builtin_amdgcn_ds_bpermute(srcA, (int)pk[1]);
  uint32_t d2 = (uint32_t)__builtin_amdgcn_ds_bpermute(srcA, (int)pk[2]);
  uint32_t d3 = (uint32_t)__builtin_amdgcn_ds_bpermute(srcA, (int)pk[3]);
  uint32_t d4 = (uint32_t)__builtin_amdgcn_ds_bpermute(srcB, (int)pk[0]);
  uint32_t d5 = (uint32_t)__builtin_amdgcn_ds_bpermute(srcB, (int)pk[1]);
  uint32_t d6 = (uint32_t)__builtin_amdgcn_ds_bpermute(srcB, (int)pk[2]);
  uint32_t d7 = (uint32_t)__builtin_amdgcn_ds_bpermute(srcB, (int)pk[3]);
  BHh.u[0] = plo(d0, d1); BHh.u[1] = plo(d2, d3);
  BHh.u[2] = plo(d4, d5); BHh.u[3] = plo(d6, d7);
  BHl.u[0] = phi(d0, d1); BHl.u[1] = phi(d2, d3);
  BHl.u[2] = phi(d4, d5); BHl.u[3] = phi(d6, d7);
}

__global__ __launch_bounds__(256, 1)
void lstm_fused(const float* __restrict__ xin,   // [B,T,32]
                const float* __restrict__ masks, // [B,T]
                const float* __restrict__ h0,    // [B,16]
                const float* __restrict__ c0,    // [B,16]
                const float* __restrict__ w_ih,  // [64,32]
                const float* __restrict__ w_hh,  // [64,16]
                const float* __restrict__ b_ih,  // [64]
                const float* __restrict__ b_hh,  // [64]
                const float* __restrict__ w_act, // [32,16]
                const float* __restrict__ b_act, // [32]
                const float* __restrict__ w_cr,  // [16]
                const float* __restrict__ b_cr,  // [1]
                float* __restrict__ actor,       // [B,T,32]
                float* __restrict__ critic,      // [B,T]
                float* __restrict__ hT,          // [B,16]
                float* __restrict__ cT)          // [B,16]
{
  __shared__ float gex[2][4][256];     // [parity][gate tile][lane*4] activated gates, 8 KB
  __shared__ float mlds[Tn * 16];      // masks [t][n], broadcast-friendly per-step read, 32 KB

  const int tid = threadIdx.x;
  const int w = tid >> 6;              // wave id = gate type (0:i 1:f 2:g 3:o)
  const int l = tid & 63;
  const int q = l >> 4;
  const int n = l & 15;
  const int b0 = blockIdx.x * 16;
  const int colbase = (q & 1) * 8;
  const bool hiQuad = (q < 2);

  // ---- stage masks -> LDS [t][n] (prologue, full __syncthreads OK here) ----
  {
    const int rown = (tid >> 4) & 15;  // which batch row this thread stages
    const int c = tid & 15;            // t-chunk
    if (w < 1 || true) {               // all 256 threads: rows*chunks = 16*16
#pragma unroll
      for (int j = 0; j < 2; ++j){
        int t = c * 32 + j * 16 + ((tid >> 8) & 0); // c*32 + j*16 .. +15, but do 4-wide
        (void)t;
      }
    }
    // simpler: 256 threads, each stages 8 consecutive float4 (32 t) of one row
    const int row = tid >> 4;          // 0..15
#pragma unroll
    for (int j = 0; j < 8; ++j){
      int t = c * 32 + j * 4;
      float4 v = *(const float4*)&masks[(size_t)(b0 + row) * Tn + t];
      mlds[(t + 0) * 16 + row] = v.x;
      mlds[(t + 1) * 16 + row] = v.y;
      mlds[(t + 2) * 16 + row] = v.z;
      mlds[(t + 3) * 16 + row] = v.w;
    }
  }
  __syncthreads();

  // ---- per-wave weight fragments: own gate only ----
  FragU wihH, wihL, whhA1, whhA2;
  f32x4 bias;
  {
    const int g = w;
    float tmp[8];
#pragma unroll
    for (int j = 0; j < 8; ++j) tmp[j] = w_ih[(g*16 + n)*32 + q*8 + j];
    split8(tmp, wihH, wihL);
#pragma unroll
    for (int j = 0; j < 8; ++j) tmp[j] = w_hh[(g*16 + n)*16 + colbase + j];
    FragU hh, hl; split8(tmp, hh, hl);
#pragma unroll
    for (int d = 0; d < 4; ++d){
      whhA1.u[d] = hiQuad ? hh.u[d] : hl.u[d];  // [Whh_hi | Whh_lo]
      whhA2.u[d] = hiQuad ? hh.u[d] : 0u;       // [Whh_hi | 0]
    }
#pragma unroll
    for (int r = 0; r < 4; ++r)
      bias[r] = b_ih[g*16 + q*4 + r] + b_hh[g*16 + q*4 + r];
  }
  // head weights: wave0/1 actor halves, wave2 critic
  FragU whA1, whA2;
  f32x4 biasA;
  float bcr = 0.0f;
  if (w < 2){
    float tmp[8];
#pragma unroll
    for (int j = 0; j < 8; ++j) tmp[j] = w_act[(w*16 + n)*16 + colbase + j];
    FragU hh, hl; split8(tmp, hh, hl);
#pragma unroll
    for (int d = 0; d < 4; ++d){
      whA1.u[d] = hiQuad ? hh.u[d] : hl.u[d];
      whA2.u[d] = hiQuad ? hh.u[d] : 0u;
    }
#pragma unroll
    for (int r = 0; r < 4; ++r) biasA[r] = b_act[w*16 + q*4 + r];
  } else if (w == 2){
    float tmp[8];
#pragma unroll
    for (int j = 0; j < 8; ++j) tmp[j] = (n == 0) ? w_cr[colbase + j] : 0.0f;
    FragU hh, hl; split8(tmp, hh, hl);
#pragma unroll
    for (int d = 0; d < 4; ++d){
      whA1.u[d] = hiQuad ? hh.u[d] : hl.u[d];
      whA2.u[d] = hiQuad ? hh.u[d] : 0u;
    }
    bcr = b_cr[0];
#pragma unroll
    for (int r = 0; r < 4; ++r) biasA[r] = 0.0f;
  }

  const int srcA = (((q & 1) * 2) * 16 + n) * 4;
  const int srcB = srcA + 64;

  // ---- initial state (redundant per wave) ----
  float cs[4], hs[4];
#pragma unroll
  for (int r = 0; r < 4; ++r){
    hs[r] = h0[(b0 + n)*16 + q*4 + r];
    cs[r] = c0[(b0 + n)*16 + q*4 + r];
  }
  uint32_t pk[4];
  packH(hs, pk);
  FragU BHh, BHl;
  buildBH(pk, srcA, srcB, BHh, BHl);

  const f32x4 zero4 = {0.f, 0.f, 0.f, 0.f};

  // ---- x prefetch: depth-4 rotating register queue ----
  const size_t xrow = (size_t)(b0 + n) * Tn * 32 + q * 8;
  float4 xA[4], xB[4];
#pragma unroll
  for (int u = 0; u < 4; ++u){
    xA[u] = *(const float4*)&xin[xrow + (size_t)u * 32];
    xB[u] = *(const float4*)&xin[xrow + (size_t)u * 32 + 4];
  }
  float mCur = mlds[0 * 16 + n];

  for (int t0 = 0; t0 < Tn; t0 += 4){
#pragma unroll
    for (int u = 0; u < 4; ++u){
      const int t = t0 + u;
      const float m = mCur;
      {
        const int tm = (t + 1 < Tn) ? (t + 1) : t;
        mCur = mlds[tm * 16 + n];            // issue early, used next step
      }

      // x fragment for own wave
      FragU Xh, Xl;
      {
        float s[8] = {xA[u].x, xA[u].y, xA[u].z, xA[u].w,
                      xB[u].x, xB[u].y, xB[u].z, xB[u].w};
        split8(s, Xh, Xl);
      }
      {
        const int tn = (t + 4 < Tn) ? (t + 4) : t;
        xA[u] = *(const float4*)&xin[xrow + (size_t)tn * 32];
        xB[u] = *(const float4*)&xin[xrow + (size_t)tn * 32 + 4];
      }

      // own-gate MFMAs: 3 x-part + 2 h-part (BH from prev step; bperm latency covered by ax)
      f32x4 ax = MF(wihH, Xh, bias);
      ax = MF(wihH, Xl, ax);
      ax = MF(wihL, Xh, ax);
      f32x4 ah = MF(whhA1, BHh, zero4);
      ah = MF(whhA2, BHl, ah);

      // heads for step t-1 (use BH(t-1), still live)
      if (t){
        const int th = t - 1;
        if (w < 2){
          f32x4 a = MF(whA1, BHh, biasA);
          a = MF(whA2, BHl, a);
          *(f32x4*)&actor[((size_t)(b0 + n) * Tn + th) * 32 + w*16 + q*4] = a;
        } else if (w == 2){
          f32x4 cc = MF(whA1, BHh, zero4);
          cc = MF(whA2, BHl, cc);
          if (q == 0) critic[(size_t)(b0 + n) * Tn + th] = cc[0] + bcr;
        }
      }

      // own-tile activation (mask folds in: gate = ax + m*ah)
      float own[4];
#pragma unroll
      for (int r = 0; r < 4; ++r){
        float gv = ax[r] + m * ah[r];
        own[r] = (w == 2) ? tanhx(gv) : sigm(gv);
      }

      // exchange activated gates (double-buffered parity, raw barrier: lgkm-only)
      const int par = t & 1;
      *(float4*)&gex[par][w][l*4] = make_float4(own[0], own[1], own[2], own[3]);
      BAR();
      float4 g0 = *(float4*)&gex[par][0][l*4];
      float4 g1 = *(float4*)&gex[par][1][l*4];
      float4 g2 = *(float4*)&gex[par][2][l*4];
      float4 g3 = *(float4*)&gex[par][3][l*4];
      const float iv[4] = {g0.x, g0.y, g0.z, g0.w};
      const float fv[4] = {g1.x, g1.y, g1.z, g1.w};
      const float gv[4] = {g2.x, g2.y, g2.z, g2.w};
      const float ov[4] = {g3.x, g3.y, g3.z, g3.w};

      // state update (redundant per wave) + pack + rebuild BH
#pragma unroll
      for (int r = 0; r < 4; ++r){
        float c2 = fv[r] * (cs[r] * m) + iv[r] * gv[r];
        float h2 = ov[r] * tanhx(c2);
        cs[r] = c2;
        hs[r] = h2;
      }
      packH(hs, pk);
      buildBH(pk, srcA, srcB, BHh, BHl);   // latency covered by next step's ax block
    }
  }

  // epilogue: heads for t = Tn-1
  {
    const int th = Tn - 1;
    if (w < 2){
      f32x4 a = MF(whA1, BHh, biasA);
      a = MF(whA2, BHl, a);
      *(f32x4*)&actor[((size_t)(b0 + n) * Tn + th) * 32 + w*16 + q*4] = a;
    } else if (w == 2){
      f32x4 cc = MF(whA1, BHh, zero4);
      cc = MF(whA2, BHl, cc);
      if (q == 0) critic[(size_t)(b0 + n) * Tn + th] = cc[0] + bcr;
    }
  }
  if (w == 3){
    *(float4*)&hT[(b0 + n)*16 + q*4] = make_float4(hs[0], hs[1], hs[2], hs[3]);
    *(float4*)&cT[(b0 + n)*16 + q*4] = make_float4(cs[0], cs[1], cs[2], cs[3]);
  }
}

extern "C" void kernel_launch(void* const* d_in, const int* in_sizes, int n_in,
                              void* d_out, int out_size, void* d_ws, size_t ws_size,
                              hipStream_t stream) {
  (void)in_sizes; (void)n_in; (void)out_size; (void)d_ws; (void)ws_size;
  const float* xin   = (const float*)d_in[0];
  const float* masks = (const float*)d_in[1];
  const float* h0    = (const float*)d_in[2];
  const float* c0    = (const float*)d_in[3];
  const float* w_ih  = (const float*)d_in[4];
  const float* w_hh  = (const float*)d_in[5];
  const float* b_ih  = (const float*)d_in[6];
  const float* b_hh  = (const float*)d_in[7];
  const float* w_act = (const float*)d_in[8];
  const float* b_act = (const float*)d_in[9];
  const float* w_cr  = (const float*)d_in[10];
  const float* b_cr  = (const float*)d_in[11];

  float* out    = (float*)d_out;
  float* actor  = out;                                   // [B,T,32]
  float* critic = out + (size_t)Bn * Tn * An;            // [B,T]
  float* hT     = critic + (size_t)Bn * Tn;              // [B,16]
  float* cT     = hT + (size_t)Bn * Hn;                  // [B,16]

  lstm_fused<<<Bn/16, 256, 0, stream>>>(xin, masks, h0, c0, w_ih, w_hh, b_ih, b_hh,
                                        w_act, b_act, w_cr, b_cr,
                                        actor, critic, hT, cT);
}